// Round 5
// baseline (800.289 us; speedup 1.0000x reference)
//
#include <hip/hip_runtime.h>
#include <stdint.h>

#define KDIM  4096    // contraction dim (cols of attention, rows of h)
#define NROWS 16384   // C*N rows of attention
#define INF   512
#define OUTF  128

typedef short bf16x8 __attribute__((ext_vector_type(8)));
typedef float f32x4  __attribute__((ext_vector_type(4)));
typedef unsigned short u16;

// ---- workspace layout (bytes). Persistent first; transients overlay part.
#define WS_MEAN 0                           // 16 B
#define WS_RSZ  16                          // 4096 f32
#define WS_H2P  16400                       // 4096*128 bf16 (1 MB), B-frag layout
#define WS_W    1064976                     // 16384*4096 bf16 (134 MB), row-major
#define WS_PART 135282704                   // K-split fp32 partials (S x 8 MB)
#define WS_LEAF WS_PART                     // transient: 524288 f32 (2 MB)
#define WS_SUB  (WS_PART + 2097152)         // transient: 512 f32
#define WS_ZP   (WS_PART + 2099200)         // transient: 32*4096 f32 (512 KB)
#define PART_STRIDE ((size_t)NROWS*OUTF)    // floats per K-split slab (8 MB)

__device__ __forceinline__ u16 f32_to_bf16_rne(float f){
  unsigned u = __float_as_uint(f);
  unsigned r = u + 0x7fffu + ((u >> 16) & 1u);
  return (u16)(r >> 16);
}

// ---- K1a: numpy-pairwise leaf sums, 1 thread per 128-element leaf -------
__global__ void __launch_bounds__(256) k_leaf(const float* __restrict__ att,
                                              float* __restrict__ leaf){
  int lf = blockIdx.x*256 + threadIdx.x;   // 0..524287
  const float* p = att + (size_t)lf*128;
  float4 u = *(const float4*)p;
  float4 v = *(const float4*)(p + 4);
  float c0=u.x, c1=u.y, c2=u.z, c3=u.w, c4=v.x, c5=v.y, c6=v.z, c7=v.w;
  #pragma unroll
  for (int j = 1; j < 16; ++j){
    float4 a = *(const float4*)(p + j*8);
    float4 b = *(const float4*)(p + j*8 + 4);
    c0+=a.x; c1+=a.y; c2+=a.z; c3+=a.w;
    c4+=b.x; c5+=b.y; c6+=b.z; c7+=b.w;
  }
  leaf[lf] = ((c0+c1)+(c2+c3)) + ((c4+c5)+(c6+c7));
}

// ---- K1b: pairwise-reduce 1024 consecutive leaves per block -------------
__global__ void __launch_bounds__(256) k_tree1(const float* __restrict__ leaf,
                                               float* __restrict__ sub){
  __shared__ float A[1024], B[512];
  int b = blockIdx.x;
  for (int i = threadIdx.x; i < 1024; i += 256) A[i] = leaf[(size_t)b*1024 + i];
  __syncthreads();
  for (int i = threadIdx.x; i < 512; i += 256) B[i] = A[2*i] + A[2*i+1];
  __syncthreads();
  if (threadIdx.x < 256) A[threadIdx.x] = B[2*threadIdx.x] + B[2*threadIdx.x+1];
  __syncthreads();
  int n = 128; float* src = A; float* dst = B;
  while (n >= 1){
    if (threadIdx.x < n) dst[threadIdx.x] = src[2*threadIdx.x] + src[2*threadIdx.x+1];
    __syncthreads();
    float* t = src; src = dst; dst = t; n >>= 1;
  }
  if (threadIdx.x == 0) sub[b] = src[0];
}

// ---- K1c: pairwise-reduce 512 subtree sums -> mean ----------------------
__global__ void __launch_bounds__(256) k_tree2(const float* __restrict__ sub,
                                               float* __restrict__ meanv){
  __shared__ float A[512], B[256];
  for (int i = threadIdx.x; i < 512; i += 256) A[i] = sub[i];
  __syncthreads();
  int n = 256; float* src = A; float* dst = B;
  while (n >= 1){
    if (threadIdx.x < n) dst[threadIdx.x] = src[2*threadIdx.x] + src[2*threadIdx.x+1];
    __syncthreads();
    float* t = src; src = dst; dst = t; n >>= 1;
  }
  if (threadIdx.x == 0) meanv[0] = src[0] * (1.0f/67108864.0f);
}

// ---- K2: fused pass — w = bf16(mask ? e : 0), Zp += e, e=(att>mean)?exp:0
// Block = 64-col stripe x 512-row split (2048 blocks).
__global__ void __launch_bounds__(256) k_w(const float* __restrict__ att,
                                           const int* __restrict__ mask,
                                           const float* __restrict__ meanv,
                                           u16* __restrict__ w,
                                           float* __restrict__ Zp){
  const float mean = meanv[0];
  const int sb = blockIdx.x & 63;       // col stripe (64 cols)
  const int rs = blockIdx.x >> 6;       // row split (512 rows)
  const int c8 = threadIdx.x & 7;       // 8 cols per thread
  const int r  = threadIdx.x >> 3;      // 0..31
  const int col = sb*64 + c8*8;
  float a0=0.f,a1=0.f,a2=0.f,a3=0.f,a4=0.f,a5=0.f,a6=0.f,a7=0.f;
  #pragma unroll 2
  for (int it = 0; it < 16; ++it){
    int row = rs*512 + it*32 + r;
    const float* p = att + (size_t)row*KDIM + col;
    const int*   q = mask + (size_t)row*KDIM + col;
    float4 u = *(const float4*)p;
    float4 v = *(const float4*)(p + 4);
    int4 mu = *(const int4*)q;
    int4 mv = *(const int4*)(q + 4);
    float e0 = (u.x > mean) ? __expf(u.x) : 0.f;
    float e1 = (u.y > mean) ? __expf(u.y) : 0.f;
    float e2 = (u.z > mean) ? __expf(u.z) : 0.f;
    float e3 = (u.w > mean) ? __expf(u.w) : 0.f;
    float e4 = (v.x > mean) ? __expf(v.x) : 0.f;
    float e5 = (v.y > mean) ? __expf(v.y) : 0.f;
    float e6 = (v.z > mean) ? __expf(v.z) : 0.f;
    float e7 = (v.w > mean) ? __expf(v.w) : 0.f;
    a0+=e0; a1+=e1; a2+=e2; a3+=e3; a4+=e4; a5+=e5; a6+=e6; a7+=e7;
    bf16x8 wv;
    wv[0]=(short)f32_to_bf16_rne(mu.x ? e0 : 0.f);
    wv[1]=(short)f32_to_bf16_rne(mu.y ? e1 : 0.f);
    wv[2]=(short)f32_to_bf16_rne(mu.z ? e2 : 0.f);
    wv[3]=(short)f32_to_bf16_rne(mu.w ? e3 : 0.f);
    wv[4]=(short)f32_to_bf16_rne(mv.x ? e4 : 0.f);
    wv[5]=(short)f32_to_bf16_rne(mv.y ? e5 : 0.f);
    wv[6]=(short)f32_to_bf16_rne(mv.z ? e6 : 0.f);
    wv[7]=(short)f32_to_bf16_rne(mv.w ? e7 : 0.f);
    *(bf16x8*)(w + (size_t)row*KDIM + col) = wv;
  }
  __shared__ float lds[32][72];
  lds[r][c8*8+0]=a0; lds[r][c8*8+1]=a1; lds[r][c8*8+2]=a2; lds[r][c8*8+3]=a3;
  lds[r][c8*8+4]=a4; lds[r][c8*8+5]=a5; lds[r][c8*8+6]=a6; lds[r][c8*8+7]=a7;
  __syncthreads();
  if (threadIdx.x < 64){
    float s = 0.f;
    #pragma unroll
    for (int rr = 0; rr < 32; ++rr) s += lds[rr][threadIdx.x];
    Zp[(size_t)rs*KDIM + sb*64 + threadIdx.x] = s;
  }
}

// ---- K2b: rsZ = 2.5 / sum(Zp) -------------------------------------------
__global__ void k_rsz(const float* __restrict__ Zp, float* __restrict__ rsZ){
  int i = blockIdx.x*256 + threadIdx.x;
  if (i < KDIM){
    float s = 0.f;
    #pragma unroll
    for (int rs = 0; rs < 32; ++rs) s += Zp[(size_t)rs*KDIM + i];
    rsZ[i] = 2.5f / s;
  }
}

// ---- K3: h2p[j][f] = bf16( rsZ[j] * (x @ W^T)[j][f] ), B-frag layout ----
__device__ __forceinline__ bf16x8 cvt8(float4 a, float4 b){
  bf16x8 r;
  r[0]=(short)f32_to_bf16_rne(a.x); r[1]=(short)f32_to_bf16_rne(a.y);
  r[2]=(short)f32_to_bf16_rne(a.z); r[3]=(short)f32_to_bf16_rne(a.w);
  r[4]=(short)f32_to_bf16_rne(b.x); r[5]=(short)f32_to_bf16_rne(b.y);
  r[6]=(short)f32_to_bf16_rne(b.z); r[7]=(short)f32_to_bf16_rne(b.w);
  return r;
}

__global__ void __launch_bounds__(256) k_h(const float* __restrict__ x,
                                           const float* __restrict__ W,
                                           const float* __restrict__ rsZ,
                                           u16* __restrict__ h2p){
  const int wave = threadIdx.x >> 6, l = threadIdx.x & 63;
  const int rt = blockIdx.x*4 + wave;   // rows 16rt..16rt+15 of x
  const int m = l & 15, q = l >> 4;
  f32x4 acc[8];
  #pragma unroll
  for (int nt = 0; nt < 8; ++nt) acc[nt] = (f32x4){0.f,0.f,0.f,0.f};
  for (int kb = 0; kb < 16; ++kb){
    const float* xp = x + (size_t)(rt*16+m)*INF + kb*32 + q*8;
    bf16x8 af = cvt8(*(const float4*)xp, *(const float4*)(xp+4));
    #pragma unroll
    for (int nt = 0; nt < 8; ++nt){
      const float* wp = W + (size_t)(nt*16+m)*INF + kb*32 + q*8;
      bf16x8 bf = cvt8(*(const float4*)wp, *(const float4*)(wp+4));
      acc[nt] = __builtin_amdgcn_mfma_f32_16x16x32_bf16(af, bf, acc[nt], 0,0,0);
    }
  }
  float4 rz = *(const float4*)(rsZ + rt*16 + q*4);
  float rzv[4] = {rz.x, rz.y, rz.z, rz.w};
  #pragma unroll
  for (int nt = 0; nt < 8; ++nt)
    #pragma unroll
    for (int r = 0; r < 4; ++r){
      int j = rt*16 + q*4 + r;                 // row of h (0..4095)
      int kb2 = j >> 5, lane_t = ((j>>3)&3)*16 + m, ii = j & 7;
      h2p[(size_t)(kb2*8 + nt)*512 + lane_t*8 + ii] =
          f32_to_bf16_rne(acc[nt][r] * rzv[r]);
    }
}

// ---- K4: h_prime = w @ h2p, 2-stage SW pipeline, K-split S --------------
template<int S>
__global__ void __launch_bounds__(256,2) k_mm(const u16* __restrict__ w,
    const u16* __restrict__ h2p, float* __restrict__ part,
    float* __restrict__ out){
  const int gw = blockIdx.x*4 + (threadIdx.x >> 6);
  const int rp = gw & 511;            // 32-row group of attention
  const int kh = gw >> 9;             // K-split index
  const int l = threadIdx.x & 63, m = l & 15, q = l >> 4;
  const int KB = 128 / S;
  const int kb0 = kh * KB;
  const size_t ro0 = (size_t)(rp*32 + m) * KDIM;
  const size_t ro1 = ro0 + (size_t)16 * KDIM;
  f32x4 acc[2][8];
  #pragma unroll
  for (int rt = 0; rt < 2; ++rt)
    #pragma unroll
    for (int nt = 0; nt < 8; ++nt) acc[rt][nt] = (f32x4){0.f,0.f,0.f,0.f};

  bf16x8 Aw0[2], Aw1[2];
  bf16x8 Bv[2][8];

#define LOADSTAGE(kb_, s_) {                                                  \
    const int kc = (kb_)*32 + q*8;                                            \
    Aw0[s_] = *(const bf16x8*)(w + ro0 + kc);                                 \
    Aw1[s_] = *(const bf16x8*)(w + ro1 + kc);                                 \
    const u16* bp_ = h2p + (size_t)((kb_)*8)*512 + l*8;                       \
    _Pragma("unroll")                                                         \
    for (int nt = 0; nt < 8; ++nt) Bv[s_][nt] = *(const bf16x8*)(bp_ + nt*512); }

#define COMPSTAGE(s_) {                                                       \
    _Pragma("unroll")                                                         \
    for (int nt = 0; nt < 8; ++nt){                                           \
      acc[0][nt] = __builtin_amdgcn_mfma_f32_16x16x32_bf16(Aw0[s_], Bv[s_][nt], acc[0][nt], 0,0,0); \
      acc[1][nt] = __builtin_amdgcn_mfma_f32_16x16x32_bf16(Aw1[s_], Bv[s_][nt], acc[1][nt], 0,0,0); } }

  LOADSTAGE(kb0, 0);
  int kb = kb0;
  for (; kb + 2 < kb0 + KB; kb += 2){
    LOADSTAGE(kb+1, 1);
    COMPSTAGE(0);
    LOADSTAGE(kb+2, 0);
    COMPSTAGE(1);
  }
  LOADSTAGE(kb0 + KB - 1, 1);
  COMPSTAGE(0);
  COMPSTAGE(1);
#undef LOADSTAGE
#undef COMPSTAGE

  if (S == 1){
    #pragma unroll
    for (int rt = 0; rt < 2; ++rt)
      #pragma unroll
      for (int nt = 0; nt < 8; ++nt)
        #pragma unroll
        for (int r = 0; r < 4; ++r){
          int i = rp*32 + rt*16 + q*4 + r;     // h_prime row
          int f = nt*16 + m;
          out[(size_t)(i & 4095)*512 + (i >> 12)*128 + f] = acc[rt][nt][r];
        }
  } else {
    float* pb = part + (size_t)kh * PART_STRIDE;
    #pragma unroll
    for (int rt = 0; rt < 2; ++rt)
      #pragma unroll
      for (int nt = 0; nt < 8; ++nt)
        #pragma unroll
        for (int r = 0; r < 4; ++r){
          int i = rp*32 + rt*16 + q*4 + r;
          int f = nt*16 + m;
          pb[(size_t)i*128 + f] = acc[rt][nt][r];
        }
  }
}

// ---- K5: reduce K-splits + reorder to (N, C*F) --------------------------
template<int S>
__global__ void __launch_bounds__(256) k_red(const float* __restrict__ part,
                                             float* __restrict__ out){
  int g = blockIdx.x*256 + threadIdx.x;   // 524288 groups of 4 floats
  int i = g >> 5;                          // h_prime row
  int fo = (g & 31) << 2;
  const float* p = part + (size_t)i*128 + fo;
  float4 s = *(const float4*)p;
  #pragma unroll
  for (int kh = 1; kh < S; ++kh){
    float4 t = *(const float4*)(p + (size_t)kh * PART_STRIDE);
    s.x += t.x; s.y += t.y; s.z += t.z; s.w += t.w;
  }
  int n = i & 4095, c = i >> 12;
  *(float4*)(out + (size_t)n*512 + c*128 + fo) = s;
}

extern "C" void kernel_launch(void* const* d_in, const int* in_sizes, int n_in,
                              void* d_out, int out_size, void* d_ws, size_t ws_size,
                              hipStream_t stream) {
  const float* x    = (const float*)d_in[0];   // f32 [4096,512]
  const float* att  = (const float*)d_in[1];   // f32 [16384,4096]
  const float* W    = (const float*)d_in[2];   // f32 [128,512]
  const int*   mask = (const int*)d_in[3];     // int 0/1 [16384,4096]
  float* out = (float*)d_out;                  // f32 [4096,512]

  char* ws = (char*)d_ws;
  float* meanv = (float*)(ws + WS_MEAN);
  float* rsZ   = (float*)(ws + WS_RSZ);
  u16*   h2p   = (u16*)(ws + WS_H2P);
  u16*   wbuf  = (u16*)(ws + WS_W);
  float* part  = (float*)(ws + WS_PART);
  float* leaf  = (float*)(ws + WS_LEAF);   // transient overlays of part
  float* sub   = (float*)(ws + WS_SUB);
  float* Zp    = (float*)(ws + WS_ZP);

  int S = 1;
  if (ws_size >= (size_t)WS_PART + 8ull*PART_STRIDE*4ull) S = 8;
  else if (ws_size >= (size_t)WS_PART + 4ull*PART_STRIDE*4ull) S = 4;

  k_leaf <<<2048, 256, 0, stream>>>(att, leaf);
  k_tree1<<<512,  256, 0, stream>>>(leaf, sub);
  k_tree2<<<1,    256, 0, stream>>>(sub, meanv);
  k_w    <<<2048, 256, 0, stream>>>(att, mask, meanv, wbuf, Zp);
  k_rsz  <<<16,   256, 0, stream>>>(Zp, rsZ);
  k_h    <<<64,   256, 0, stream>>>(x, W, rsZ, h2p);

  switch (S){
    case 8:
      k_mm<8><<<1024, 256, 0, stream>>>(wbuf, h2p, part, out);
      k_red<8><<<2048, 256, 0, stream>>>(part, out);
      break;
    case 4:
      k_mm<4><<<512, 256, 0, stream>>>(wbuf, h2p, part, out);
      k_red<4><<<2048, 256, 0, stream>>>(part, out);
      break;
    default:
      k_mm<1><<<128, 256, 0, stream>>>(wbuf, h2p, part, out);
      break;
  }
}

// Round 6
// 792.269 us; speedup vs baseline: 1.0101x; 1.0101x over previous
//
#include <hip/hip_runtime.h>
#include <stdint.h>

#define KDIM  4096    // contraction dim (cols of attention, rows of h)
#define NROWS 16384   // C*N rows of attention
#define INF   512
#define OUTF  128

typedef short bf16x8 __attribute__((ext_vector_type(8)));
typedef float f32x4  __attribute__((ext_vector_type(4)));
typedef unsigned short u16;

// ---- workspace layout (bytes). Persistent first; transients overlay part.
#define WS_MEAN 0                           // 16 B
#define WS_RSZ  16                          // 4096 f32
#define WS_H2P  16400                       // 4096*128 bf16 (1 MB), B-frag layout
#define WS_W    1064976                     // 16384*4096 bf16 (134 MB), row-major
#define WS_PART 135282704                   // K-split fp32 partials (S x 8.4 MB)
#define WS_LEAF WS_PART                     // transient: 524288 f32 (2 MB)
#define WS_SUB  (WS_PART + 2097152)         // transient: 512 f32
#define WS_ZP   (WS_PART + 4194304)         // transient: 1024*4096 f32 (16 MB)
#define PART_STRIDE ((size_t)NROWS*OUTF)    // floats per K-split slab

__device__ __forceinline__ u16 f32_to_bf16_rne(float f){
  unsigned u = __float_as_uint(f);
  unsigned r = u + 0x7fffu + ((u >> 16) & 1u);
  return (u16)(r >> 16);
}

// ---- K1a: numpy-pairwise leaf sums, 1 thread per 128-element leaf -------
__global__ void __launch_bounds__(256) k_leaf(const float* __restrict__ att,
                                              float* __restrict__ leaf){
  int lf = blockIdx.x*256 + threadIdx.x;   // 0..524287
  const float* p = att + (size_t)lf*128;
  float4 u = *(const float4*)p;
  float4 v = *(const float4*)(p + 4);
  float c0=u.x, c1=u.y, c2=u.z, c3=u.w, c4=v.x, c5=v.y, c6=v.z, c7=v.w;
  #pragma unroll
  for (int j = 1; j < 16; ++j){
    float4 a = *(const float4*)(p + j*8);
    float4 b = *(const float4*)(p + j*8 + 4);
    c0+=a.x; c1+=a.y; c2+=a.z; c3+=a.w;
    c4+=b.x; c5+=b.y; c6+=b.z; c7+=b.w;
  }
  leaf[lf] = ((c0+c1)+(c2+c3)) + ((c4+c5)+(c6+c7));
}

// ---- K1b: pairwise-reduce 1024 consecutive leaves per block -------------
__global__ void __launch_bounds__(256) k_tree1(const float* __restrict__ leaf,
                                               float* __restrict__ sub){
  __shared__ float A[1024], B[512];
  int b = blockIdx.x;
  for (int i = threadIdx.x; i < 1024; i += 256) A[i] = leaf[(size_t)b*1024 + i];
  __syncthreads();
  for (int i = threadIdx.x; i < 512; i += 256) B[i] = A[2*i] + A[2*i+1];
  __syncthreads();
  if (threadIdx.x < 256) A[threadIdx.x] = B[2*threadIdx.x] + B[2*threadIdx.x+1];
  __syncthreads();
  int n = 128; float* src = A; float* dst = B;
  while (n >= 1){
    if (threadIdx.x < n) dst[threadIdx.x] = src[2*threadIdx.x] + src[2*threadIdx.x+1];
    __syncthreads();
    float* t = src; src = dst; dst = t; n >>= 1;
  }
  if (threadIdx.x == 0) sub[b] = src[0];
}

// ---- K1c: pairwise-reduce 512 subtree sums -> mean ----------------------
__global__ void __launch_bounds__(256) k_tree2(const float* __restrict__ sub,
                                               float* __restrict__ meanv){
  __shared__ float A[512], B[256];
  for (int i = threadIdx.x; i < 512; i += 256) A[i] = sub[i];
  __syncthreads();
  int n = 256; float* src = A; float* dst = B;
  while (n >= 1){
    if (threadIdx.x < n) dst[threadIdx.x] = src[2*threadIdx.x] + src[2*threadIdx.x+1];
    __syncthreads();
    float* t = src; src = dst; dst = t; n >>= 1;
  }
  if (threadIdx.x == 0) meanv[0] = src[0] * (1.0f/67108864.0f);
}

// ---- K2: fused, page-sequential. Block = 16 full rows. ------------------
// w = bf16(mask ? e : 0); Zp[blk][col] = per-block column sums of e.
__global__ void __launch_bounds__(256) k_w(const float* __restrict__ att,
                                           const int* __restrict__ mask,
                                           const float* __restrict__ meanv,
                                           u16* __restrict__ w,
                                           float* __restrict__ Zp){
  const float mean = meanv[0];
  const int b = blockIdx.x;            // rows b*16 .. b*16+15
  const int t = threadIdx.x;
  float z[16];
  #pragma unroll
  for (int i = 0; i < 16; ++i) z[i] = 0.f;

  #pragma unroll 2
  for (int r = 0; r < 16; ++r){
    const size_t ro = ((size_t)b*16 + r) * KDIM;
    #pragma unroll
    for (int p = 0; p < 4; ++p){
      const int c = p*1024 + t*4;
      float4 u = *(const float4*)(att + ro + c);
      int4  mu = *(const int4*)(mask + ro + c);
      float e0 = (u.x > mean) ? __expf(u.x) : 0.f;
      float e1 = (u.y > mean) ? __expf(u.y) : 0.f;
      float e2 = (u.z > mean) ? __expf(u.z) : 0.f;
      float e3 = (u.w > mean) ? __expf(u.w) : 0.f;
      z[p*4+0]+=e0; z[p*4+1]+=e1; z[p*4+2]+=e2; z[p*4+3]+=e3;
      ushort4 wv;
      wv.x = f32_to_bf16_rne(mu.x ? e0 : 0.f);
      wv.y = f32_to_bf16_rne(mu.y ? e1 : 0.f);
      wv.z = f32_to_bf16_rne(mu.z ? e2 : 0.f);
      wv.w = f32_to_bf16_rne(mu.w ? e3 : 0.f);
      *(ushort4*)(w + ro + c) = wv;
    }
  }
  #pragma unroll
  for (int p = 0; p < 4; ++p){
    float4 zv = {z[p*4+0], z[p*4+1], z[p*4+2], z[p*4+3]};
    *(float4*)(Zp + (size_t)b*KDIM + p*1024 + t*4) = zv;
  }
}

// ---- K2b: rsZ = 2.5 / sum over 1024 Zp slabs (16 indep chains) ----------
__global__ void __launch_bounds__(256) k_rsz(const float* __restrict__ Zp,
                                             float* __restrict__ rsZ){
  int col = blockIdx.x*256 + threadIdx.x;   // 4096 cols via 16 blocks
  float a[16];
  #pragma unroll
  for (int i = 0; i < 16; ++i) a[i] = 0.f;
  for (int bb = 0; bb < 1024; bb += 16){
    #pragma unroll
    for (int u = 0; u < 16; ++u)
      a[u] += Zp[(size_t)(bb+u)*KDIM + col];
  }
  float s = (((a[0]+a[1])+(a[2]+a[3])) + ((a[4]+a[5])+(a[6]+a[7])))
          + (((a[8]+a[9])+(a[10]+a[11])) + ((a[12]+a[13])+(a[14]+a[15])));
  rsZ[col] = 2.5f / s;
}

// ---- K3: h2p[j][f] = bf16( rsZ[j] * (x @ W^T)[j][f] ), B-frag layout ----
__device__ __forceinline__ bf16x8 cvt8(float4 a, float4 b){
  bf16x8 r;
  r[0]=(short)f32_to_bf16_rne(a.x); r[1]=(short)f32_to_bf16_rne(a.y);
  r[2]=(short)f32_to_bf16_rne(a.z); r[3]=(short)f32_to_bf16_rne(a.w);
  r[4]=(short)f32_to_bf16_rne(b.x); r[5]=(short)f32_to_bf16_rne(b.y);
  r[6]=(short)f32_to_bf16_rne(b.z); r[7]=(short)f32_to_bf16_rne(b.w);
  return r;
}

__global__ void __launch_bounds__(256) k_h(const float* __restrict__ x,
                                           const float* __restrict__ W,
                                           const float* __restrict__ rsZ,
                                           u16* __restrict__ h2p){
  const int wave = threadIdx.x >> 6, l = threadIdx.x & 63;
  const int rt = blockIdx.x*4 + wave;   // rows 16rt..16rt+15 of x
  const int m = l & 15, q = l >> 4;
  f32x4 acc[8];
  #pragma unroll
  for (int nt = 0; nt < 8; ++nt) acc[nt] = (f32x4){0.f,0.f,0.f,0.f};
  for (int kb = 0; kb < 16; ++kb){
    const float* xp = x + (size_t)(rt*16+m)*INF + kb*32 + q*8;
    bf16x8 af = cvt8(*(const float4*)xp, *(const float4*)(xp+4));
    #pragma unroll
    for (int nt = 0; nt < 8; ++nt){
      const float* wp = W + (size_t)(nt*16+m)*INF + kb*32 + q*8;
      bf16x8 bf = cvt8(*(const float4*)wp, *(const float4*)(wp+4));
      acc[nt] = __builtin_amdgcn_mfma_f32_16x16x32_bf16(af, bf, acc[nt], 0,0,0);
    }
  }
  float4 rz = *(const float4*)(rsZ + rt*16 + q*4);
  float rzv[4] = {rz.x, rz.y, rz.z, rz.w};
  #pragma unroll
  for (int nt = 0; nt < 8; ++nt)
    #pragma unroll
    for (int r = 0; r < 4; ++r){
      int j = rt*16 + q*4 + r;                 // row of h (0..4095)
      int kb2 = j >> 5, lane_t = ((j>>3)&3)*16 + m, ii = j & 7;
      h2p[(size_t)(kb2*8 + nt)*512 + lane_t*8 + ii] =
          f32_to_bf16_rne(acc[nt][r] * rzv[r]);
    }
}

// ---- K4: h_prime = w @ h2p, 2-stage SW pipeline, K-split S --------------
template<int S>
__global__ void __launch_bounds__(256,2) k_mm(const u16* __restrict__ w,
    const u16* __restrict__ h2p, float* __restrict__ part,
    float* __restrict__ out){
  const int gw = blockIdx.x*4 + (threadIdx.x >> 6);
  const int rp = gw & 511;            // 32-row group of attention
  const int kh = gw >> 9;             // K-split index
  const int l = threadIdx.x & 63, m = l & 15, q = l >> 4;
  const int KB = 128 / S;
  const int kb0 = kh * KB;
  const size_t ro0 = (size_t)(rp*32 + m) * KDIM;
  const size_t ro1 = ro0 + (size_t)16 * KDIM;
  f32x4 acc[2][8];
  #pragma unroll
  for (int rt = 0; rt < 2; ++rt)
    #pragma unroll
    for (int nt = 0; nt < 8; ++nt) acc[rt][nt] = (f32x4){0.f,0.f,0.f,0.f};

  bf16x8 Aw0[2], Aw1[2];
  bf16x8 Bv[2][8];

#define LOADSTAGE(kb_, s_) {                                                  \
    const int kc = (kb_)*32 + q*8;                                            \
    Aw0[s_] = *(const bf16x8*)(w + ro0 + kc);                                 \
    Aw1[s_] = *(const bf16x8*)(w + ro1 + kc);                                 \
    const u16* bp_ = h2p + (size_t)((kb_)*8)*512 + l*8;                       \
    _Pragma("unroll")                                                         \
    for (int nt = 0; nt < 8; ++nt) Bv[s_][nt] = *(const bf16x8*)(bp_ + nt*512); }

#define COMPSTAGE(s_) {                                                       \
    _Pragma("unroll")                                                         \
    for (int nt = 0; nt < 8; ++nt){                                           \
      acc[0][nt] = __builtin_amdgcn_mfma_f32_16x16x32_bf16(Aw0[s_], Bv[s_][nt], acc[0][nt], 0,0,0); \
      acc[1][nt] = __builtin_amdgcn_mfma_f32_16x16x32_bf16(Aw1[s_], Bv[s_][nt], acc[1][nt], 0,0,0); } }

  LOADSTAGE(kb0, 0);
  int kb = kb0;
  for (; kb + 2 < kb0 + KB; kb += 2){
    LOADSTAGE(kb+1, 1);
    COMPSTAGE(0);
    LOADSTAGE(kb+2, 0);
    COMPSTAGE(1);
  }
  LOADSTAGE(kb0 + KB - 1, 1);
  COMPSTAGE(0);
  COMPSTAGE(1);
#undef LOADSTAGE
#undef COMPSTAGE

  if (S == 1){
    #pragma unroll
    for (int rt = 0; rt < 2; ++rt)
      #pragma unroll
      for (int nt = 0; nt < 8; ++nt)
        #pragma unroll
        for (int r = 0; r < 4; ++r){
          int i = rp*32 + rt*16 + q*4 + r;     // h_prime row
          int f = nt*16 + m;
          out[(size_t)(i & 4095)*512 + (i >> 12)*128 + f] = acc[rt][nt][r];
        }
  } else {
    float* pb = part + (size_t)kh * PART_STRIDE;
    #pragma unroll
    for (int rt = 0; rt < 2; ++rt)
      #pragma unroll
      for (int nt = 0; nt < 8; ++nt)
        #pragma unroll
        for (int r = 0; r < 4; ++r){
          int i = rp*32 + rt*16 + q*4 + r;
          int f = nt*16 + m;
          pb[(size_t)i*128 + f] = acc[rt][nt][r];
        }
  }
}

// ---- K5: reduce K-splits + reorder to (N, C*F) --------------------------
template<int S>
__global__ void __launch_bounds__(256) k_red(const float* __restrict__ part,
                                             float* __restrict__ out){
  int g = blockIdx.x*256 + threadIdx.x;   // 524288 groups of 4 floats
  int i = g >> 5;                          // h_prime row
  int fo = (g & 31) << 2;
  const float* p = part + (size_t)i*128 + fo;
  float4 s = *(const float4*)p;
  #pragma unroll
  for (int kh = 1; kh < S; ++kh){
    float4 t = *(const float4*)(p + (size_t)kh * PART_STRIDE);
    s.x += t.x; s.y += t.y; s.z += t.z; s.w += t.w;
  }
  int n = i & 4095, c = i >> 12;
  *(float4*)(out + (size_t)n*512 + c*128 + fo) = s;
}

extern "C" void kernel_launch(void* const* d_in, const int* in_sizes, int n_in,
                              void* d_out, int out_size, void* d_ws, size_t ws_size,
                              hipStream_t stream) {
  const float* x    = (const float*)d_in[0];   // f32 [4096,512]
  const float* att  = (const float*)d_in[1];   // f32 [16384,4096]
  const float* W    = (const float*)d_in[2];   // f32 [128,512]
  const int*   mask = (const int*)d_in[3];     // int 0/1 [16384,4096]
  float* out = (float*)d_out;                  // f32 [4096,512]

  char* ws = (char*)d_ws;
  float* meanv = (float*)(ws + WS_MEAN);
  float* rsZ   = (float*)(ws + WS_RSZ);
  u16*   h2p   = (u16*)(ws + WS_H2P);
  u16*   wbuf  = (u16*)(ws + WS_W);
  float* part  = (float*)(ws + WS_PART);
  float* leaf  = (float*)(ws + WS_LEAF);   // transient overlays of part
  float* sub   = (float*)(ws + WS_SUB);
  float* Zp    = (float*)(ws + WS_ZP);

  int S = 1;
  if (ws_size >= (size_t)WS_PART + 8ull*PART_STRIDE*4ull) S = 8;
  else if (ws_size >= (size_t)WS_PART + 4ull*PART_STRIDE*4ull) S = 4;

  k_leaf <<<2048, 256, 0, stream>>>(att, leaf);
  k_tree1<<<512,  256, 0, stream>>>(leaf, sub);
  k_tree2<<<1,    256, 0, stream>>>(sub, meanv);
  k_w    <<<1024, 256, 0, stream>>>(att, mask, meanv, wbuf, Zp);
  k_rsz  <<<16,   256, 0, stream>>>(Zp, rsZ);
  k_h    <<<64,   256, 0, stream>>>(x, W, rsZ, h2p);

  switch (S){
    case 8:
      k_mm<8><<<1024, 256, 0, stream>>>(wbuf, h2p, part, out);
      k_red<8><<<2048, 256, 0, stream>>>(part, out);
      break;
    case 4:
      k_mm<4><<<512, 256, 0, stream>>>(wbuf, h2p, part, out);
      k_red<4><<<2048, 256, 0, stream>>>(part, out);
      break;
    default:
      k_mm<1><<<128, 256, 0, stream>>>(wbuf, h2p, part, out);
      break;
  }
}